// Round 3
// baseline (69.855 us; speedup 1.0000x reference)
//
#include <hip/hip_runtime.h>
#include <hip/hip_bf16.h>
#include <stdint.h>

typedef __bf16 bf16x8 __attribute__((ext_vector_type(8)));
typedef float f32x4 __attribute__((ext_vector_type(4)));

#define KDIM 256
#define MB 4480          // padded rows per batch (35 * 128)
#define MTOT 17920       // 4 * MB
#define NPIX 16384       // 4*64*64
#define QKVS 768         // fused q/k/v row stride

__device__ __forceinline__ float b2f(ushort u){
    union { float f; uint32_t i; } x; x.i = ((uint32_t)u) << 16; return x.f;
}
__device__ __forceinline__ ushort f2b(float f){
    uint32_t u = __float_as_uint(f);
    uint32_t r = (u + 0x7fffu + ((u >> 16) & 1u)) >> 16;
    return (ushort)r;
}

// --------- Kernel A: single-pass x read -> bf16 CL transpose + LN partials --
// block = (b*64 + h), 256 threads. Reads x[b, :, h, :] (256c x 64w) with
// 8-full-line wave loads, LDS-transposes, writes xt coalesced, emits per-h
// partial sum/sumsq per channel.
__global__ __launch_bounds__(256)
void ln_fuse(const float* __restrict__ x, ushort* __restrict__ xt,
             float* __restrict__ psum, float* __restrict__ psum2){
    __shared__ ushort sh[256 * 68];
    const int bid = blockIdx.x;
    const int b = bid >> 6, h = bid & 63;
    const int tid = threadIdx.x;
    const float* xb = x + (size_t)b * 256 * 4096 + h * 64;
    const int csub = tid >> 4, w4 = tid & 15;
#pragma unroll
    for (int i = 0; i < 16; ++i){
        int c = i * 16 + csub;
        float4 v = *(const float4*)(xb + (size_t)c * 4096 + w4 * 4);
        ushort4 u; u.x = f2b(v.x); u.y = f2b(v.y); u.z = f2b(v.z); u.w = f2b(v.w);
        *(ushort4*)&sh[c * 68 + w4 * 4] = u;
    }
    __syncthreads();
    float s = 0.f, s2 = 0.f;
    size_t rowbase = ((size_t)b * MB + (size_t)(h + 1) * 66 + 1) * 256;
#pragma unroll 8
    for (int w = 0; w < 64; ++w){
        ushort u = sh[tid * 68 + w];
        float f = b2f(u);
        s += f; s2 += f * f;
        xt[rowbase + (size_t)w * 256 + tid] = u;
    }
    psum [bid * 256 + tid] = s;
    psum2[bid * 256 + tid] = s2;
}

// --------- B1: finalize LN stats per (b,c) ---------------------------------
__global__ __launch_bounds__(256)
void stats_fin(const float* __restrict__ psum, const float* __restrict__ psum2,
               float* __restrict__ rstd_g, float* __restrict__ mrv_g,
               ushort* __restrict__ mb_g){
    int b = blockIdx.x, tid = threadIdx.x;
    float S = 0.f, S2 = 0.f;
    for (int h = 0; h < 64; ++h){
        S  += psum [(b * 64 + h) * 256 + tid];
        S2 += psum2[(b * 64 + h) * 256 + tid];
    }
    float m  = S * (1.f / 4096.f);
    float v  = S2 * (1.f / 4096.f) - m * m;
    float rv = rsqrtf(v + 1e-5f);
    rstd_g[b * 256 + tid] = rv;
    mrv_g [b * 256 + tid] = m * rv;
    mb_g  [b * 256 + tid] = f2b(m);
}

// --------- B2: per-b scaled weights + folded bias + pad fill (block-range) --
// [0,192):   qkv weight transpose, x4 b-copies scaled by rv[b,k] (q also /16)
// [192,256): Wo transpose (unscaled)
// [256,268): folded bias matvec: biasp[b][n] = qs*(bias[n] - sum_c mrv*W[c,n])
// [268,316): fill 384 pad/tail rows per b with bf16(mean[b,c])
__global__ __launch_bounds__(256)
void prep2(const float* __restrict__ Wq, const float* __restrict__ bq,
           const float* __restrict__ Wk, const float* __restrict__ bk,
           const float* __restrict__ Wv, const float* __restrict__ bv,
           const float* __restrict__ Wo,
           const float* __restrict__ rstd_g, const float* __restrict__ mrv_g,
           const ushort* __restrict__ mb_g,
           ushort* __restrict__ wtq, ushort* __restrict__ wot,
           float* __restrict__ biasp, ushort* __restrict__ xt){
    __shared__ float sh[32 * 33];
    const int bid = blockIdx.x, tid = threadIdx.x;
    if (bid < 192){
        int mat = bid / 64, tile = bid % 64;
        int ti = tile & 7, tj = tile >> 3;
        const float* src = (mat == 0) ? Wq : (mat == 1) ? Wk : Wv;
        float qs = (mat == 0) ? 0.0625f : 1.0f;
        int tx = tid & 31, ty = tid >> 5;
#pragma unroll
        for (int i = 0; i < 4; ++i)
            sh[(ty + i * 8) * 33 + tx] =
                src[(size_t)(tj * 32 + ty + i * 8) * 256 + ti * 32 + tx] * qs;
        __syncthreads();
        int k = tj * 32 + tx;
#pragma unroll
        for (int b = 0; b < 4; ++b){
            float rv = rstd_g[b * 256 + k];
#pragma unroll
            for (int i = 0; i < 4; ++i){
                int n = mat * 256 + ti * 32 + ty + i * 8;
                wtq[((size_t)b * 768 + n) * 256 + k] =
                    f2b(sh[tx * 33 + ty + i * 8] * rv);
            }
        }
    } else if (bid < 256){
        int tile = bid - 192;
        int ti = tile & 7, tj = tile >> 3;
        int tx = tid & 31, ty = tid >> 5;
#pragma unroll
        for (int i = 0; i < 4; ++i)
            sh[(ty + i * 8) * 33 + tx] =
                Wo[(size_t)(tj * 32 + ty + i * 8) * 256 + ti * 32 + tx];
        __syncthreads();
#pragma unroll
        for (int i = 0; i < 4; ++i)
            wot[(size_t)(ti * 32 + ty + i * 8) * 256 + tj * 32 + tx] =
                f2b(sh[tx * 33 + ty + i * 8]);
    } else if (bid < 268){
        int t = bid - 256;                 // 12 blocks: b*3 + mat
        int b = t / 3, mat = t % 3;
        const float* W  = (mat == 0) ? Wq : (mat == 1) ? Wk : Wv;
        const float* bb = (mat == 0) ? bq : (mat == 1) ? bk : bv;
        float qs = (mat == 0) ? 0.0625f : 1.0f;
        float acc = 0.f;
        for (int c = 0; c < 256; ++c)
            acc += mrv_g[b * 256 + c] * W[(size_t)c * 256 + tid];
        biasp[b * 768 + mat * 256 + tid] = (bb[tid] - acc) * qs;
    } else {
        int t = bid - 268;                 // 48 blocks x 32 rows = 1536 rows
        int b = t / 12, seg = t % 12;
        ushort mb = mb_g[b * 256 + tid];
        for (int r = 0; r < 32; ++r){
            int j = seg * 32 + r;          // 0..383 within batch b
            int row;
            if (j < 260){
                int h66, w66;
                if (j < 66)       { h66 = 0;       w66 = j; }
                else if (j < 132) { h66 = 65;      w66 = j - 66; }
                else if (j < 196) { h66 = j - 131; w66 = 0; }
                else              { h66 = j - 195; w66 = 65; }
                row = h66 * 66 + w66;
            } else row = 4356 + (j - 260);
            xt[((size_t)b * MB + row) * 256 + tid] = mb;
        }
    }
}

// --------------------------- MFMA GEMM ---------------------------------
// Z[x][y] = dot(X[x][0:256], Y[y][0:256])  (both row-major, K contiguous)
// MODE 0: per-b weights: Y base += (x0/MB)*768*256; zb[x*768+y]=bf16(acc+bias)
// MODE 1: zf[((y>>12)*256 + x)*4096 + (y&4095)] = acc + bias[x]  (out, NCHW)
template<int MODE>
__global__ __launch_bounds__(256, 2)
void gemm_nt(const ushort* __restrict__ X, const ushort* __restrict__ Y,
             const float* __restrict__ bias,
             ushort* __restrict__ zb, float* __restrict__ zf){
    __shared__ ushort ldsX[2][128 * 64];
    __shared__ ushort ldsY[2][128 * 64];
    const int tid  = threadIdx.x;
    const int lane = tid & 63;
    const int wid  = tid >> 6;
    const int wm   = wid >> 1, wn = wid & 1;
    const int x0   = blockIdx.x * 128, y0 = blockIdx.y * 128;
    const int bsel = (MODE == 0) ? (x0 / MB) : 0;
    const ushort* Yb   = (MODE == 0) ? Y + (size_t)bsel * 768 * 256 : Y;
    const float* biasb = (MODE == 0) ? bias + bsel * 768 : bias;

    auto stage = [&](int buf, int k0){
#pragma unroll
        for (int i = 0; i < 4; ++i){
            int f   = i * 256 + tid;          // dest 16B-chunk index
            int row = f >> 3, cp = f & 7;
            int cs  = cp ^ (row & 7);         // source chunk (involution)
            const ushort* gx = X  + (size_t)(x0 + row) * KDIM + k0 + cs * 8;
            const ushort* gy = Yb + (size_t)(y0 + row) * KDIM + k0 + cs * 8;
            __builtin_amdgcn_global_load_lds(
                (const __attribute__((address_space(1))) void*)gx,
                (__attribute__((address_space(3))) void*)&ldsX[buf][f * 8], 16, 0, 0);
            __builtin_amdgcn_global_load_lds(
                (const __attribute__((address_space(1))) void*)gy,
                (__attribute__((address_space(3))) void*)&ldsY[buf][f * 8], 16, 0, 0);
        }
    };

    f32x4 acc[4][4];
#pragma unroll
    for (int i = 0; i < 4; ++i)
#pragma unroll
        for (int j = 0; j < 4; ++j) acc[i][j] = f32x4{0.f, 0.f, 0.f, 0.f};

    stage(0, 0);
    int buf = 0;
    for (int t = 0; t < 4; ++t){            // K = 256 = 4 * 64
        __syncthreads();
        if (t < 3) stage(buf ^ 1, (t + 1) * 64);
#pragma unroll
        for (int kk = 0; kk < 2; ++kk){
            bf16x8 xa[4], yb[4];
#pragma unroll
            for (int fm = 0; fm < 4; ++fm){
                int r = wm * 64 + fm * 16 + (lane & 15);
                int c = kk * 4 + (lane >> 4);
                xa[fm] = *(const bf16x8*)&ldsX[buf][(r * 8 + (c ^ (r & 7))) * 8];
            }
#pragma unroll
            for (int fn = 0; fn < 4; ++fn){
                int r = wn * 64 + fn * 16 + (lane & 15);
                int c = kk * 4 + (lane >> 4);
                yb[fn] = *(const bf16x8*)&ldsY[buf][(r * 8 + (c ^ (r & 7))) * 8];
            }
#pragma unroll
            for (int fm = 0; fm < 4; ++fm)
#pragma unroll
                for (int fn = 0; fn < 4; ++fn)
                    acc[fm][fn] = __builtin_amdgcn_mfma_f32_16x16x32_bf16(
                        xa[fm], yb[fn], acc[fm][fn], 0, 0, 0);
        }
        buf ^= 1;
    }

#pragma unroll
    for (int fm = 0; fm < 4; ++fm){
#pragma unroll
        for (int fn = 0; fn < 4; ++fn){
            int xr = x0 + wm * 64 + fm * 16 + ((lane >> 4) << 2);
            int yc = y0 + wn * 64 + fn * 16 + (lane & 15);
            if (MODE == 0){
                float bv = biasb[yc];
#pragma unroll
                for (int r = 0; r < 4; ++r)
                    zb[(size_t)(xr + r) * QKVS + yc] = f2b(acc[fm][fn][r] + bv);
            } else {
                int bpix = yc >> 12, hw = yc & 4095;
#pragma unroll
                for (int r = 0; r < 4; ++r){
                    int ch = xr + r;
                    zf[((size_t)(bpix * 256 + ch)) * 4096 + hw] =
                        acc[fm][fn][r] + bias[ch];
                }
            }
        }
    }
}

// ------------------- 3x3 window attention: one wave per pixel ---------------
__global__ __launch_bounds__(256)
void attn_win(const ushort* __restrict__ qkv, ushort* __restrict__ ctx){
    int pix  = blockIdx.x * 4 + (threadIdx.x >> 6);
    int lane = threadIdx.x & 63;
    int b = pix >> 12, hw = pix & 4095;
    int h = hw >> 6, w = hw & 63;
    size_t base = (size_t)b * MB;
    size_t crow = base + (size_t)(h + 1) * 66 + (w + 1);

    ushort4 q4 = *(const ushort4*)(qkv + crow * QKVS + lane * 4);
    float q0 = b2f(q4.x), q1 = b2f(q4.y), q2 = b2f(q4.z), q3 = b2f(q4.w);

    float lg[9];
    size_t rows[9];
#pragma unroll
    for (int n = 0; n < 9; ++n){
        int dh = n / 3, dw = n % 3;
        size_t row = base + (size_t)(h + dh) * 66 + (w + dw);
        rows[n] = row;
        ushort4 k4 = *(const ushort4*)(qkv + row * QKVS + 256 + lane * 4);
        float d = q0 * b2f(k4.x) + q1 * b2f(k4.y) + q2 * b2f(k4.z) + q3 * b2f(k4.w);
#pragma unroll
        for (int off = 32; off; off >>= 1) d += __shfl_xor(d, off);
        lg[n] = d;
    }
    float m = lg[0];
#pragma unroll
    for (int n = 1; n < 9; ++n) m = fmaxf(m, lg[n]);
    float e[9], s = 0.f;
#pragma unroll
    for (int n = 0; n < 9; ++n){ e[n] = __expf(lg[n] - m); s += e[n]; }
    float inv = 1.f / s;

    float c0 = 0.f, c1 = 0.f, c2 = 0.f, c3 = 0.f;
#pragma unroll
    for (int n = 0; n < 9; ++n){
        float a = e[n] * inv;
        ushort4 v4 = *(const ushort4*)(qkv + rows[n] * QKVS + 512 + lane * 4);
        c0 += a * b2f(v4.x); c1 += a * b2f(v4.y);
        c2 += a * b2f(v4.z); c3 += a * b2f(v4.w);
    }
    ushort4 o; o.x = f2b(c0); o.y = f2b(c1); o.z = f2b(c2); o.w = f2b(c3);
    *(ushort4*)(ctx + (size_t)pix * 256 + lane * 4) = o;
}

// ---------------------------------------------------------------------------
extern "C" void kernel_launch(void* const* d_in, const int* in_sizes, int n_in,
                              void* d_out, int out_size, void* d_ws, size_t ws_size,
                              hipStream_t stream){
    const float* x  = (const float*)d_in[0];
    const float* Wq = (const float*)d_in[1];
    const float* bq = (const float*)d_in[2];
    const float* Wk = (const float*)d_in[3];
    const float* bk = (const float*)d_in[4];
    const float* Wv = (const float*)d_in[5];
    const float* bv = (const float*)d_in[6];
    const float* Wo = (const float*)d_in[7];
    const float* bo = (const float*)d_in[8];
    float* out = (float*)d_out;

    char* ws = (char*)d_ws;
    ushort* wtq    = (ushort*)(ws);                // [4][768][256] bf16
    ushort* wot    = (ushort*)(ws + 1572864);      // [256][256] bf16
    float*  biasp  = (float*) (ws + 1703936);      // [4][768]
    float*  psum   = (float*) (ws + 1716224);      // [256][256]
    float*  psum2  = (float*) (ws + 1978368);      // [256][256]
    float*  rstd_g = (float*) (ws + 2240512);      // [4][256]
    float*  mrv_g  = (float*) (ws + 2244608);      // [4][256]
    ushort* mb_g   = (ushort*)(ws + 2248704);      // [4][256]
    ushort* xt     = (ushort*)(ws + 2250752);      // [MTOT][256] bf16
    ushort* qkv    = (ushort*)(ws + 11425792);     // [MTOT][768] bf16
    ushort* ctx    = (ushort*)(ws + 38950912);     // [NPIX][256] bf16

    ln_fuse<<<256, 256, 0, stream>>>(x, xt, psum, psum2);
    stats_fin<<<4, 256, 0, stream>>>(psum, psum2, rstd_g, mrv_g, mb_g);
    prep2<<<316, 256, 0, stream>>>(Wq, bq, Wk, bk, Wv, bv, Wo,
                                   rstd_g, mrv_g, mb_g, wtq, wot, biasp, xt);

    dim3 g1(140, 6);   // MTOT/128 x 768/128
    gemm_nt<0><<<g1, 256, 0, stream>>>(xt, wtq, biasp, qkv, nullptr);

    attn_win<<<4096, 256, 0, stream>>>(qkv, ctx);

    dim3 g2(2, 128);   // 256/128 x NPIX/128
    gemm_nt<1><<<g2, 256, 0, stream>>>(wot, ctx, bo, nullptr, out);
}

// Round 4
// 63.766 us; speedup vs baseline: 1.0955x; 1.0955x over previous
//
#include <hip/hip_runtime.h>
#include <hip/hip_bf16.h>
#include <stdint.h>

typedef __bf16 bf16x8 __attribute__((ext_vector_type(8)));
typedef float f32x4 __attribute__((ext_vector_type(4)));

#define KDIM 256
#define MB 4480          // padded rows per batch (35 * 128)
#define MTOT 17920       // 4 * MB
#define QKVS 768         // fused q/k/v row stride

__device__ __forceinline__ float b2f(ushort u){
    union { float f; uint32_t i; } x; x.i = ((uint32_t)u) << 16; return x.f;
}
__device__ __forceinline__ ushort f2b(float f){
    uint32_t u = __float_as_uint(f);
    uint32_t r = (u + 0x7fffu + ((u >> 16) & 1u)) >> 16;
    return (ushort)r;
}

// --------- Kernel P1: single x pass -> bf16 CL transpose + fp32 LN partials -
// 512 blocks: (b, h, c-half of 128). Reads x[b, ch:ch+128, h, :] coalesced,
// LDS-transposes, writes xt rows with 16B stores, emits psum/psum2[(b,h)][c].
__global__ __launch_bounds__(256)
void ln_fuse(const float* __restrict__ x, ushort* __restrict__ xt,
             float* __restrict__ psum, float* __restrict__ psum2){
    __shared__ ushort sh[128 * 68];
    __shared__ float ssum[16 * 132], ssum2[16 * 132];
    const int bid = blockIdx.x;
    const int b = bid >> 7, rem = bid & 127, h = rem >> 1, ch = (rem & 1) * 128;
    const int tid = threadIdx.x;
    const int csub = tid >> 4, w4 = tid & 15;
#pragma unroll
    for (int i = 0; i < 8; ++i){
        int c = csub + 16 * i;            // local channel 0..127
        float4 v = *(const float4*)(x + ((size_t)(b * 256 + ch + c)) * 4096
                                      + h * 64 + w4 * 4);
        ushort4 u; u.x = f2b(v.x); u.y = f2b(v.y); u.z = f2b(v.z); u.w = f2b(v.w);
        *(ushort4*)&sh[c * 68 + w4 * 4] = u;
        ssum [w4 * 132 + c] = v.x + v.y + v.z + v.w;
        ssum2[w4 * 132 + c] = v.x * v.x + v.y * v.y + v.z * v.z + v.w * v.w;
    }
    __syncthreads();
    if (tid < 128){
        float S = 0.f, S2 = 0.f;
#pragma unroll
        for (int j = 0; j < 16; ++j){ S += ssum[j * 132 + tid]; S2 += ssum2[j * 132 + tid]; }
        psum [(b * 64 + h) * 256 + ch + tid] = S;
        psum2[(b * 64 + h) * 256 + ch + tid] = S2;
    }
    // store xt: 4 passes, each thread writes 8 channels (16B) of one w-row
    const int c16 = tid & 15, w16 = tid >> 4;
#pragma unroll
    for (int p = 0; p < 4; ++p){
        int w = p * 16 + w16;
        union { ushort u[8]; uint4 v; } r;
#pragma unroll
        for (int j = 0; j < 8; ++j) r.u[j] = sh[(c16 * 8 + j) * 68 + w];
        size_t row = (size_t)b * MB + (size_t)(h + 1) * 66 + (w + 1);
        *(uint4*)(xt + row * 256 + ch + c16 * 8) = r.v;
    }
}

// --------- P2: per-b scaled weights + folded bias + pad fill (block-range) --
// each block recomputes the stats it needs from psum/psum2 (L2-resident)
// [0,192):   qkv weight transpose, 4 b-copies scaled by rv[b,k] (q also /16)
// [192,256): Wo transpose (unscaled)
// [256,268): folded bias: biasp[b][n] = qs*(bias[n] - sum_c m*rv*W[c,n])
// [268,316): fill 384 pad/tail rows per b with bf16(mean[b,c])
__global__ __launch_bounds__(256)
void prep2(const float* __restrict__ Wq, const float* __restrict__ bq,
           const float* __restrict__ Wk, const float* __restrict__ bk,
           const float* __restrict__ Wv, const float* __restrict__ bv,
           const float* __restrict__ Wo,
           const float* __restrict__ psum, const float* __restrict__ psum2,
           ushort* __restrict__ wtq, ushort* __restrict__ wot,
           float* __restrict__ biasp, ushort* __restrict__ xt){
    __shared__ float shW[32 * 33];
    __shared__ float shS[8 * 32], shS2[8 * 32], shRV[4 * 32], shM[256];
    const int bid = blockIdx.x, tid = threadIdx.x;
    if (bid < 192){
        int mat = bid / 64, tile = bid % 64;
        int ti = tile & 7, tj = tile >> 3;
        // recompute rv[b, tj*32 + kk] for all 4 b
        {
            int kk = tid & 31, idx = tid >> 5;        // idx: b*2 + h-half
            int b = idx >> 1, h0 = (idx & 1) * 32;
            float S = 0.f, S2 = 0.f;
            for (int r = 0; r < 32; ++r){
                int off = (b * 64 + h0 + r) * 256 + tj * 32 + kk;
                S += psum[off]; S2 += psum2[off];
            }
            shS[idx * 32 + kk] = S; shS2[idx * 32 + kk] = S2;
        }
        __syncthreads();
        if (tid < 128){
            int b = tid >> 5, kk = tid & 31;
            float S  = shS [(b * 2) * 32 + kk] + shS [(b * 2 + 1) * 32 + kk];
            float S2 = shS2[(b * 2) * 32 + kk] + shS2[(b * 2 + 1) * 32 + kk];
            float m = S * (1.f / 4096.f);
            float v = S2 * (1.f / 4096.f) - m * m;
            shRV[b * 32 + kk] = rsqrtf(v + 1e-5f);
        }
        const float* src = (mat == 0) ? Wq : (mat == 1) ? Wk : Wv;
        float qs = (mat == 0) ? 0.0625f : 1.0f;
        int tx = tid & 31, ty = tid >> 5;
#pragma unroll
        for (int i = 0; i < 4; ++i)
            shW[(ty + i * 8) * 33 + tx] =
                src[(size_t)(tj * 32 + ty + i * 8) * 256 + ti * 32 + tx] * qs;
        __syncthreads();
#pragma unroll
        for (int b = 0; b < 4; ++b){
            float rv = shRV[b * 32 + tx];
#pragma unroll
            for (int i = 0; i < 4; ++i){
                int n = mat * 256 + ti * 32 + ty + i * 8;
                wtq[((size_t)b * 768 + n) * 256 + tj * 32 + tx] =
                    f2b(shW[tx * 33 + ty + i * 8] * rv);
            }
        }
    } else if (bid < 256){
        int tile = bid - 192;
        int ti = tile & 7, tj = tile >> 3;
        int tx = tid & 31, ty = tid >> 5;
#pragma unroll
        for (int i = 0; i < 4; ++i)
            shW[(ty + i * 8) * 33 + tx] =
                Wo[(size_t)(tj * 32 + ty + i * 8) * 256 + ti * 32 + tx];
        __syncthreads();
#pragma unroll
        for (int i = 0; i < 4; ++i)
            wot[(size_t)(ti * 32 + ty + i * 8) * 256 + tj * 32 + tx] =
                f2b(shW[tx * 33 + ty + i * 8]);
    } else if (bid < 268){
        int t = bid - 256;
        int b = t / 3, mat = t % 3;
        // recompute m*rv for c = tid
        float S = 0.f, S2 = 0.f;
        for (int h = 0; h < 64; ++h){
            S += psum[(b * 64 + h) * 256 + tid]; S2 += psum2[(b * 64 + h) * 256 + tid];
        }
        float m = S * (1.f / 4096.f);
        float v = S2 * (1.f / 4096.f) - m * m;
        shM[tid] = m * rsqrtf(v + 1e-5f);
        __syncthreads();
        const float* W  = (mat == 0) ? Wq : (mat == 1) ? Wk : Wv;
        const float* bb = (mat == 0) ? bq : (mat == 1) ? bk : bv;
        float qs = (mat == 0) ? 0.0625f : 1.0f;
        float acc = 0.f;
        for (int c = 0; c < 256; ++c)
            acc += shM[c] * W[(size_t)c * 256 + tid];
        biasp[b * 768 + mat * 256 + tid] = (bb[tid] - acc) * qs;
    } else {
        int t = bid - 268;                 // 48 blocks x 32 rows = 1536 rows
        int b = t / 12, seg = t % 12;
        float S = 0.f;
        for (int h = 0; h < 64; ++h) S += psum[(b * 64 + h) * 256 + tid];
        ushort mb = f2b(S * (1.f / 4096.f));
        for (int r = 0; r < 32; ++r){
            int j = seg * 32 + r;          // 0..383 within batch b
            int row;
            if (j < 260){
                int h66, w66;
                if (j < 66)       { h66 = 0;       w66 = j; }
                else if (j < 132) { h66 = 65;      w66 = j - 66; }
                else if (j < 196) { h66 = j - 131; w66 = 0; }
                else              { h66 = j - 195; w66 = 65; }
                row = h66 * 66 + w66;
            } else row = 4356 + (j - 260);
            xt[((size_t)b * MB + row) * 256 + tid] = mb;
        }
    }
}

// --------------------------- MFMA GEMM ---------------------------------
// Z[x][y] = dot(X[x][0:256], Y[y][0:256])  (both row-major, K contiguous)
// MODE 0: N-tile fastest in grid (A-panel L2 reuse); per-b weights via x0/MB
// MODE 1: zf[((y>>12)*256 + x)*4096 + (y&4095)] = acc + bias[x]  (out, NCHW)
template<int MODE>
__global__ __launch_bounds__(256, 2)
void gemm_nt(const ushort* __restrict__ X, const ushort* __restrict__ Y,
             const float* __restrict__ bias,
             ushort* __restrict__ zb, float* __restrict__ zf){
    __shared__ ushort ldsX[2][128 * 64];
    __shared__ ushort ldsY[2][128 * 64];
    const int tid  = threadIdx.x;
    const int lane = tid & 63;
    const int wid  = tid >> 6;
    const int wm   = wid >> 1, wn = wid & 1;
    const int x0   = (MODE == 0 ? blockIdx.y : blockIdx.x) * 128;
    const int y0   = (MODE == 0 ? blockIdx.x : blockIdx.y) * 128;
    const int bsel = (MODE == 0) ? (x0 / MB) : 0;
    const ushort* Yb   = (MODE == 0) ? Y + (size_t)bsel * 768 * 256 : Y;
    const float* biasb = (MODE == 0) ? bias + bsel * 768 : bias;

    auto stage = [&](int buf, int k0){
#pragma unroll
        for (int i = 0; i < 4; ++i){
            int f   = i * 256 + tid;          // dest 16B-chunk index
            int row = f >> 3, cp = f & 7;
            int cs  = cp ^ (row & 7);         // source chunk (involution)
            const ushort* gx = X  + (size_t)(x0 + row) * KDIM + k0 + cs * 8;
            const ushort* gy = Yb + (size_t)(y0 + row) * KDIM + k0 + cs * 8;
            __builtin_amdgcn_global_load_lds(
                (const __attribute__((address_space(1))) void*)gx,
                (__attribute__((address_space(3))) void*)&ldsX[buf][f * 8], 16, 0, 0);
            __builtin_amdgcn_global_load_lds(
                (const __attribute__((address_space(1))) void*)gy,
                (__attribute__((address_space(3))) void*)&ldsY[buf][f * 8], 16, 0, 0);
        }
    };

    f32x4 acc[4][4];
#pragma unroll
    for (int i = 0; i < 4; ++i)
#pragma unroll
        for (int j = 0; j < 4; ++j) acc[i][j] = f32x4{0.f, 0.f, 0.f, 0.f};

    stage(0, 0);
    int buf = 0;
    for (int t = 0; t < 4; ++t){            // K = 256 = 4 * 64
        __syncthreads();
        if (t < 3) stage(buf ^ 1, (t + 1) * 64);
#pragma unroll
        for (int kk = 0; kk < 2; ++kk){
            bf16x8 xa[4], yb[4];
#pragma unroll
            for (int fm = 0; fm < 4; ++fm){
                int r = wm * 64 + fm * 16 + (lane & 15);
                int c = kk * 4 + (lane >> 4);
                xa[fm] = *(const bf16x8*)&ldsX[buf][(r * 8 + (c ^ (r & 7))) * 8];
            }
#pragma unroll
            for (int fn = 0; fn < 4; ++fn){
                int r = wn * 64 + fn * 16 + (lane & 15);
                int c = kk * 4 + (lane >> 4);
                yb[fn] = *(const bf16x8*)&ldsY[buf][(r * 8 + (c ^ (r & 7))) * 8];
            }
#pragma unroll
            for (int fm = 0; fm < 4; ++fm)
#pragma unroll
                for (int fn = 0; fn < 4; ++fn)
                    acc[fm][fn] = __builtin_amdgcn_mfma_f32_16x16x32_bf16(
                        xa[fm], yb[fn], acc[fm][fn], 0, 0, 0);
        }
        buf ^= 1;
    }

#pragma unroll
    for (int fm = 0; fm < 4; ++fm){
#pragma unroll
        for (int fn = 0; fn < 4; ++fn){
            int xr = x0 + wm * 64 + fm * 16 + ((lane >> 4) << 2);
            int yc = y0 + wn * 64 + fn * 16 + (lane & 15);
            if (MODE == 0){
                float bv = biasb[yc];
#pragma unroll
                for (int r = 0; r < 4; ++r)
                    zb[(size_t)(xr + r) * QKVS + yc] = f2b(acc[fm][fn][r] + bv);
            } else {
                int bpix = yc >> 12, hw = yc & 4095;
#pragma unroll
                for (int r = 0; r < 4; ++r){
                    int ch = xr + r;
                    zf[((size_t)(bpix * 256 + ch)) * 4096 + hw] =
                        acc[fm][fn][r] + bias[ch];
                }
            }
        }
    }
}

// ------------------- 3x3 window attention: one wave per pixel ---------------
__global__ __launch_bounds__(256)
void attn_win(const ushort* __restrict__ qkv, ushort* __restrict__ ctx){
    int pix  = blockIdx.x * 4 + (threadIdx.x >> 6);
    int lane = threadIdx.x & 63;
    int b = pix >> 12, hw = pix & 4095;
    int h = hw >> 6, w = hw & 63;
    size_t base = (size_t)b * MB;
    size_t crow = base + (size_t)(h + 1) * 66 + (w + 1);

    ushort4 q4 = *(const ushort4*)(qkv + crow * QKVS + lane * 4);
    float q0 = b2f(q4.x), q1 = b2f(q4.y), q2 = b2f(q4.z), q3 = b2f(q4.w);

    float lg[9];
    size_t rows[9];
#pragma unroll
    for (int n = 0; n < 9; ++n){
        int dh = n / 3, dw = n % 3;
        size_t row = base + (size_t)(h + dh) * 66 + (w + dw);
        rows[n] = row;
        ushort4 k4 = *(const ushort4*)(qkv + row * QKVS + 256 + lane * 4);
        float d = q0 * b2f(k4.x) + q1 * b2f(k4.y) + q2 * b2f(k4.z) + q3 * b2f(k4.w);
#pragma unroll
        for (int off = 32; off; off >>= 1) d += __shfl_xor(d, off);
        lg[n] = d;
    }
    float m = lg[0];
#pragma unroll
    for (int n = 1; n < 9; ++n) m = fmaxf(m, lg[n]);
    float e[9], s = 0.f;
#pragma unroll
    for (int n = 0; n < 9; ++n){ e[n] = __expf(lg[n] - m); s += e[n]; }
    float inv = 1.f / s;

    float c0 = 0.f, c1 = 0.f, c2 = 0.f, c3 = 0.f;
#pragma unroll
    for (int n = 0; n < 9; ++n){
        float a = e[n] * inv;
        ushort4 v4 = *(const ushort4*)(qkv + rows[n] * QKVS + 512 + lane * 4);
        c0 += a * b2f(v4.x); c1 += a * b2f(v4.y);
        c2 += a * b2f(v4.z); c3 += a * b2f(v4.w);
    }
    ushort4 o; o.x = f2b(c0); o.y = f2b(c1); o.z = f2b(c2); o.w = f2b(c3);
    *(ushort4*)(ctx + (size_t)pix * 256 + lane * 4) = o;
}

// ---------------------------------------------------------------------------
extern "C" void kernel_launch(void* const* d_in, const int* in_sizes, int n_in,
                              void* d_out, int out_size, void* d_ws, size_t ws_size,
                              hipStream_t stream){
    const float* x  = (const float*)d_in[0];
    const float* Wq = (const float*)d_in[1];
    const float* bq = (const float*)d_in[2];
    const float* Wk = (const float*)d_in[3];
    const float* bk = (const float*)d_in[4];
    const float* Wv = (const float*)d_in[5];
    const float* bv = (const float*)d_in[6];
    const float* Wo = (const float*)d_in[7];
    const float* bo = (const float*)d_in[8];
    float* out = (float*)d_out;

    char* ws = (char*)d_ws;
    ushort* wtq    = (ushort*)(ws);                // [4][768][256] bf16
    ushort* wot    = (ushort*)(ws + 1572864);      // [256][256] bf16
    float*  biasp  = (float*) (ws + 1703936);      // [4][768]
    float*  psum   = (float*) (ws + 1716224);      // [256][256]
    float*  psum2  = (float*) (ws + 1978368);      // [256][256]
    ushort* xt     = (ushort*)(ws + 2240512);      // [MTOT][256] bf16
    ushort* qkv    = (ushort*)(ws + 11415552);     // [MTOT][768] bf16
    ushort* ctx    = (ushort*)(ws + 38940672);     // [NPIX][256] bf16

    ln_fuse<<<512, 256, 0, stream>>>(x, xt, psum, psum2);
    prep2<<<316, 256, 0, stream>>>(Wq, bq, Wk, bk, Wv, bv, Wo,
                                   psum, psum2, wtq, wot, biasp, xt);

    dim3 g1(6, 140);   // N-tiles fastest -> A-panel L2 reuse
    gemm_nt<0><<<g1, 256, 0, stream>>>(xt, wtq, biasp, qkv, nullptr);

    attn_win<<<4096, 256, 0, stream>>>(qkv, ctx);

    dim3 g2(2, 128);
    gemm_nt<1><<<g2, 256, 0, stream>>>(wot, ctx, bo, nullptr, out);
}

// Round 5
// 59.282 us; speedup vs baseline: 1.1784x; 1.0756x over previous
//
#include <hip/hip_runtime.h>
#include <hip/hip_bf16.h>
#include <stdint.h>

typedef __bf16 bf16x8 __attribute__((ext_vector_type(8)));
typedef float f32x4 __attribute__((ext_vector_type(4)));

#define KDIM 256
#define MB 4608          // padded rows per batch (18 * 256)
#define MTOT 18432       // 4 * MB
#define QKVS 768         // fused q/k/v row stride

__device__ __forceinline__ float b2f(ushort u){
    union { float f; uint32_t i; } x; x.i = ((uint32_t)u) << 16; return x.f;
}
__device__ __forceinline__ ushort f2b(float f){
    uint32_t u = __float_as_uint(f);
    uint32_t r = (u + 0x7fffu + ((u >> 16) & 1u)) >> 16;
    return (ushort)r;
}

// --------- Kernel P1: single x pass -> bf16 CL transpose + fp32 LN partials -
__global__ __launch_bounds__(256)
void ln_fuse(const float* __restrict__ x, ushort* __restrict__ xt,
             float* __restrict__ psum, float* __restrict__ psum2){
    __shared__ ushort sh[128 * 68];
    __shared__ float ssum[16 * 132], ssum2[16 * 132];
    const int bid = blockIdx.x;
    const int b = bid >> 7, rem = bid & 127, h = rem >> 1, ch = (rem & 1) * 128;
    const int tid = threadIdx.x;
    const int csub = tid >> 4, w4 = tid & 15;
#pragma unroll
    for (int i = 0; i < 8; ++i){
        int c = csub + 16 * i;            // local channel 0..127
        float4 v = *(const float4*)(x + ((size_t)(b * 256 + ch + c)) * 4096
                                      + h * 64 + w4 * 4);
        ushort4 u; u.x = f2b(v.x); u.y = f2b(v.y); u.z = f2b(v.z); u.w = f2b(v.w);
        *(ushort4*)&sh[c * 68 + w4 * 4] = u;
        ssum [w4 * 132 + c] = v.x + v.y + v.z + v.w;
        ssum2[w4 * 132 + c] = v.x * v.x + v.y * v.y + v.z * v.z + v.w * v.w;
    }
    __syncthreads();
    if (tid < 128){
        float S = 0.f, S2 = 0.f;
#pragma unroll
        for (int j = 0; j < 16; ++j){ S += ssum[j * 132 + tid]; S2 += ssum2[j * 132 + tid]; }
        psum [(b * 64 + h) * 256 + ch + tid] = S;
        psum2[(b * 64 + h) * 256 + ch + tid] = S2;
    }
    const int c16 = tid & 15, w16 = tid >> 4;
#pragma unroll
    for (int p = 0; p < 4; ++p){
        int w = p * 16 + w16;
        union { ushort u[8]; uint4 v; } r;
#pragma unroll
        for (int j = 0; j < 8; ++j) r.u[j] = sh[(c16 * 8 + j) * 68 + w];
        size_t row = (size_t)b * MB + (size_t)(h + 1) * 66 + (w + 1);
        *(uint4*)(xt + row * 256 + ch + c16 * 8) = r.v;
    }
}

// --------- P2: per-b scaled weights + folded bias + pad fill (block-range) --
// [0,192):   qkv weight transpose, 4 b-copies scaled by rv[b,k] (q also /16)
// [192,256): Wo transpose (unscaled)
// [256,268): folded bias: biasp[b][n] = qs*(bias[n] - sum_c m*rv*W[c,n])
// [268,332): fill 512 pad/tail rows per b with bf16(mean[b,c])
__global__ __launch_bounds__(256)
void prep2(const float* __restrict__ Wq, const float* __restrict__ bq,
           const float* __restrict__ Wk, const float* __restrict__ bk,
           const float* __restrict__ Wv, const float* __restrict__ bv,
           const float* __restrict__ Wo,
           const float* __restrict__ psum, const float* __restrict__ psum2,
           ushort* __restrict__ wtq, ushort* __restrict__ wot,
           float* __restrict__ biasp, ushort* __restrict__ xt){
    __shared__ float shW[32 * 33];
    __shared__ float shS[8 * 32], shS2[8 * 32], shRV[4 * 32], shM[256];
    const int bid = blockIdx.x, tid = threadIdx.x;
    if (bid < 192){
        int mat = bid / 64, tile = bid % 64;
        int ti = tile & 7, tj = tile >> 3;
        {
            int kk = tid & 31, idx = tid >> 5;        // idx: b*2 + h-half
            int b = idx >> 1, h0 = (idx & 1) * 32;
            float S = 0.f, S2 = 0.f;
            for (int r = 0; r < 32; ++r){
                int off = (b * 64 + h0 + r) * 256 + tj * 32 + kk;
                S += psum[off]; S2 += psum2[off];
            }
            shS[idx * 32 + kk] = S; shS2[idx * 32 + kk] = S2;
        }
        __syncthreads();
        if (tid < 128){
            int b = tid >> 5, kk = tid & 31;
            float S  = shS [(b * 2) * 32 + kk] + shS [(b * 2 + 1) * 32 + kk];
            float S2 = shS2[(b * 2) * 32 + kk] + shS2[(b * 2 + 1) * 32 + kk];
            float m = S * (1.f / 4096.f);
            float v = S2 * (1.f / 4096.f) - m * m;
            shRV[b * 32 + kk] = rsqrtf(v + 1e-5f);
        }
        const float* src = (mat == 0) ? Wq : (mat == 1) ? Wk : Wv;
        float qs = (mat == 0) ? 0.0625f : 1.0f;
        int tx = tid & 31, ty = tid >> 5;
#pragma unroll
        for (int i = 0; i < 4; ++i)
            shW[(ty + i * 8) * 33 + tx] =
                src[(size_t)(tj * 32 + ty + i * 8) * 256 + ti * 32 + tx] * qs;
        __syncthreads();
#pragma unroll
        for (int b = 0; b < 4; ++b){
            float rv = shRV[b * 32 + tx];
#pragma unroll
            for (int i = 0; i < 4; ++i){
                int n = mat * 256 + ti * 32 + ty + i * 8;
                wtq[((size_t)b * 768 + n) * 256 + tj * 32 + tx] =
                    f2b(shW[tx * 33 + ty + i * 8] * rv);
            }
        }
    } else if (bid < 256){
        int tile = bid - 192;
        int ti = tile & 7, tj = tile >> 3;
        int tx = tid & 31, ty = tid >> 5;
#pragma unroll
        for (int i = 0; i < 4; ++i)
            shW[(ty + i * 8) * 33 + tx] =
                Wo[(size_t)(tj * 32 + ty + i * 8) * 256 + ti * 32 + tx];
        __syncthreads();
#pragma unroll
        for (int i = 0; i < 4; ++i)
            wot[(size_t)(ti * 32 + ty + i * 8) * 256 + tj * 32 + tx] =
                f2b(shW[tx * 33 + ty + i * 8]);
    } else if (bid < 268){
        int t = bid - 256;
        int b = t / 3, mat = t % 3;
        float S = 0.f, S2 = 0.f;
        for (int h = 0; h < 64; ++h){
            S += psum[(b * 64 + h) * 256 + tid]; S2 += psum2[(b * 64 + h) * 256 + tid];
        }
        float m = S * (1.f / 4096.f);
        float v = S2 * (1.f / 4096.f) - m * m;
        shM[tid] = m * rsqrtf(v + 1e-5f);
        __syncthreads();
        const float* W  = (mat == 0) ? Wq : (mat == 1) ? Wk : Wv;
        const float* bb = (mat == 0) ? bq : (mat == 1) ? bk : bv;
        float qs = (mat == 0) ? 0.0625f : 1.0f;
        float acc = 0.f;
        for (int c = 0; c < 256; ++c)
            acc += shM[c] * W[(size_t)c * 256 + tid];
        biasp[b * 768 + mat * 256 + tid] = (bb[tid] - acc) * qs;
    } else {
        int t = bid - 268;                 // 64 blocks x 32 rows = 2048 rows
        int b = t / 16, seg = t % 16;
        float S = 0.f;
        for (int h = 0; h < 64; ++h) S += psum[(b * 64 + h) * 256 + tid];
        ushort mb = f2b(S * (1.f / 4096.f));
        for (int r = 0; r < 32; ++r){
            int j = seg * 32 + r;          // 0..511 within batch b
            int row;
            if (j < 260){
                int h66, w66;
                if (j < 66)       { h66 = 0;       w66 = j; }
                else if (j < 132) { h66 = 65;      w66 = j - 66; }
                else if (j < 196) { h66 = j - 131; w66 = 0; }
                else              { h66 = j - 195; w66 = 65; }
                row = h66 * 66 + w66;
            } else row = 4356 + (j - 260);
            xt[((size_t)b * MB + row) * 256 + tid] = mb;
        }
    }
}

// ------------- QKV GEMM: 256x256 tile, BK=64, 8 waves, counted vmcnt --------
// qkv[x][y] = dot(xt[x][:], wtq[b][y][:]) + biasp[b][y], b = x / MB
__global__ __launch_bounds__(512, 1)
void gemm_qkv(const ushort* __restrict__ X, const ushort* __restrict__ Y,
              const float* __restrict__ bias, ushort* __restrict__ zb){
    __shared__ ushort ldsA[2][256 * 64];
    __shared__ ushort ldsB[2][256 * 64];
    const int tid  = threadIdx.x;
    const int lane = tid & 63;
    const int wid  = tid >> 6;            // 0..7
    const int wm   = wid >> 2;            // 0..1 : rows wm*128
    const int wn   = wid & 3;             // 0..3 : cols wn*64
    const int id    = blockIdx.x;
    const int mtile = id % 72, ntile = id / 72;   // m-fastest dispatch
    const int x0 = mtile * 256, y0 = ntile * 256;
    const int bsel = x0 / MB;
    const ushort* Yb   = Y + ((size_t)bsel * QKVS + y0) * 256;
    const float* biasb = bias + bsel * 768;

    // T2 chunk swizzle: LDS dest linear, global source chunk pre-swizzled,
    // reads apply the same XOR (16B-chunk granularity, 8 chunks/row).
    auto stage = [&](int buf, int k0){
#pragma unroll
        for (int i = 0; i < 4; ++i){
            int f   = i * 512 + tid;          // chunk 0..2047
            int row = f >> 3, cp = f & 7;
            int cs  = cp ^ (row & 7);
            const ushort* ga = X  + (size_t)(x0 + row) * KDIM + k0 + cs * 8;
            const ushort* gb = Yb + (size_t)row        * KDIM + k0 + cs * 8;
            __builtin_amdgcn_global_load_lds(
                (const __attribute__((address_space(1))) void*)ga,
                (__attribute__((address_space(3))) void*)&ldsA[buf][f * 8], 16, 0, 0);
            __builtin_amdgcn_global_load_lds(
                (const __attribute__((address_space(1))) void*)gb,
                (__attribute__((address_space(3))) void*)&ldsB[buf][f * 8], 16, 0, 0);
        }
    };

    f32x4 acc[8][4];
#pragma unroll
    for (int i = 0; i < 8; ++i)
#pragma unroll
        for (int j = 0; j < 4; ++j) acc[i][j] = f32x4{0.f, 0.f, 0.f, 0.f};

    stage(0, 0);
    stage(1, 64);
#pragma unroll
    for (int t = 0; t < 4; ++t){
        // wait for K-tile t only (8 loads/thread of the NEXT tile may fly)
        if (t < 3) asm volatile("s_waitcnt vmcnt(8)" ::: "memory");
        else       asm volatile("s_waitcnt vmcnt(0)" ::: "memory");
        __builtin_amdgcn_sched_barrier(0);
        __builtin_amdgcn_s_barrier();
        __builtin_amdgcn_sched_barrier(0);
        const int buf = t & 1;
        __builtin_amdgcn_s_setprio(1);
#pragma unroll
        for (int kk = 0; kk < 2; ++kk){
            bf16x8 af[8], bf[4];
#pragma unroll
            for (int fm = 0; fm < 8; ++fm){
                int r = wm * 128 + fm * 16 + (lane & 15);
                int c = kk * 4 + (lane >> 4);
                af[fm] = *(const bf16x8*)&ldsA[buf][(r * 8 + (c ^ (r & 7))) * 8];
            }
#pragma unroll
            for (int fn = 0; fn < 4; ++fn){
                int r = wn * 64 + fn * 16 + (lane & 15);
                int c = kk * 4 + (lane >> 4);
                bf[fn] = *(const bf16x8*)&ldsB[buf][(r * 8 + (c ^ (r & 7))) * 8];
            }
#pragma unroll
            for (int fm = 0; fm < 8; ++fm)
#pragma unroll
                for (int fn = 0; fn < 4; ++fn)
                    acc[fm][fn] = __builtin_amdgcn_mfma_f32_16x16x32_bf16(
                        af[fm], bf[fn], acc[fm][fn], 0, 0, 0);
        }
        __builtin_amdgcn_s_setprio(0);
        __builtin_amdgcn_sched_barrier(0);
        __builtin_amdgcn_s_barrier();
        __builtin_amdgcn_sched_barrier(0);
        if (t < 2) stage(t & 1, (t + 2) * 64);
    }

    // epilogue: col = lane&15 (B-row), row = (lane>>4)*4 + r (A-row)
#pragma unroll
    for (int fm = 0; fm < 8; ++fm){
#pragma unroll
        for (int fn = 0; fn < 4; ++fn){
            int xr = x0 + wm * 128 + fm * 16 + ((lane >> 4) << 2);
            int yc = y0 + wn * 64 + fn * 16 + (lane & 15);
            float bv = biasb[yc];
#pragma unroll
            for (int r = 0; r < 4; ++r)
                zb[(size_t)(xr + r) * QKVS + yc] = f2b(acc[fm][fn][r] + bv);
        }
    }
}

// ------------- out GEMM (128x128, NCHW epilogue), unchanged structure -------
__global__ __launch_bounds__(256, 2)
void gemm_out(const ushort* __restrict__ X, const ushort* __restrict__ Y,
              const float* __restrict__ bias, float* __restrict__ zf){
    __shared__ ushort ldsX[2][128 * 64];
    __shared__ ushort ldsY[2][128 * 64];
    const int tid  = threadIdx.x;
    const int lane = tid & 63;
    const int wid  = tid >> 6;
    const int wm   = wid >> 1, wn = wid & 1;
    const int x0   = blockIdx.x * 128, y0 = blockIdx.y * 128;

    auto stage = [&](int buf, int k0){
#pragma unroll
        for (int i = 0; i < 4; ++i){
            int f   = i * 256 + tid;
            int row = f >> 3, cp = f & 7;
            int cs  = cp ^ (row & 7);
            const ushort* gx = X + (size_t)(x0 + row) * KDIM + k0 + cs * 8;
            const ushort* gy = Y + (size_t)(y0 + row) * KDIM + k0 + cs * 8;
            __builtin_amdgcn_global_load_lds(
                (const __attribute__((address_space(1))) void*)gx,
                (__attribute__((address_space(3))) void*)&ldsX[buf][f * 8], 16, 0, 0);
            __builtin_amdgcn_global_load_lds(
                (const __attribute__((address_space(1))) void*)gy,
                (__attribute__((address_space(3))) void*)&ldsY[buf][f * 8], 16, 0, 0);
        }
    };

    f32x4 acc[4][4];
#pragma unroll
    for (int i = 0; i < 4; ++i)
#pragma unroll
        for (int j = 0; j < 4; ++j) acc[i][j] = f32x4{0.f, 0.f, 0.f, 0.f};

    stage(0, 0);
    int buf = 0;
    for (int t = 0; t < 4; ++t){
        __syncthreads();
        if (t < 3) stage(buf ^ 1, (t + 1) * 64);
#pragma unroll
        for (int kk = 0; kk < 2; ++kk){
            bf16x8 xa[4], yb[4];
#pragma unroll
            for (int fm = 0; fm < 4; ++fm){
                int r = wm * 64 + fm * 16 + (lane & 15);
                int c = kk * 4 + (lane >> 4);
                xa[fm] = *(const bf16x8*)&ldsX[buf][(r * 8 + (c ^ (r & 7))) * 8];
            }
#pragma unroll
            for (int fn = 0; fn < 4; ++fn){
                int r = wn * 64 + fn * 16 + (lane & 15);
                int c = kk * 4 + (lane >> 4);
                yb[fn] = *(const bf16x8*)&ldsY[buf][(r * 8 + (c ^ (r & 7))) * 8];
            }
#pragma unroll
            for (int fm = 0; fm < 4; ++fm)
#pragma unroll
                for (int fn = 0; fn < 4; ++fn)
                    acc[fm][fn] = __builtin_amdgcn_mfma_f32_16x16x32_bf16(
                        xa[fm], yb[fn], acc[fm][fn], 0, 0, 0);
        }
        buf ^= 1;
    }

#pragma unroll
    for (int fm = 0; fm < 4; ++fm){
#pragma unroll
        for (int fn = 0; fn < 4; ++fn){
            int xr = x0 + wm * 64 + fm * 16 + ((lane >> 4) << 2);
            int yc = y0 + wn * 64 + fn * 16 + (lane & 15);
            int bpix = yc >> 12, hw = yc & 4095;
#pragma unroll
            for (int r = 0; r < 4; ++r){
                int ch = xr + r;
                zf[((size_t)(bpix * 256 + ch)) * 4096 + hw] =
                    acc[fm][fn][r] + bias[ch];
            }
        }
    }
}

// ------------------- 3x3 window attention: one wave per pixel ---------------
__global__ __launch_bounds__(256)
void attn_win(const ushort* __restrict__ qkv, ushort* __restrict__ ctx){
    int pix  = blockIdx.x * 4 + (threadIdx.x >> 6);
    int lane = threadIdx.x & 63;
    int b = pix >> 12, hw = pix & 4095;
    int h = hw >> 6, w = hw & 63;
    size_t base = (size_t)b * MB;
    size_t crow = base + (size_t)(h + 1) * 66 + (w + 1);

    ushort4 q4 = *(const ushort4*)(qkv + crow * QKVS + lane * 4);
    float q0 = b2f(q4.x), q1 = b2f(q4.y), q2 = b2f(q4.z), q3 = b2f(q4.w);

    float lg[9];
    size_t rows[9];
#pragma unroll
    for (int n = 0; n < 9; ++n){
        int dh = n / 3, dw = n % 3;
        size_t row = base + (size_t)(h + dh) * 66 + (w + dw);
        rows[n] = row;
        ushort4 k4 = *(const ushort4*)(qkv + row * QKVS + 256 + lane * 4);
        float d = q0 * b2f(k4.x) + q1 * b2f(k4.y) + q2 * b2f(k4.z) + q3 * b2f(k4.w);
#pragma unroll
        for (int off = 32; off; off >>= 1) d += __shfl_xor(d, off);
        lg[n] = d;
    }
    float m = lg[0];
#pragma unroll
    for (int n = 1; n < 9; ++n) m = fmaxf(m, lg[n]);
    float e[9], s = 0.f;
#pragma unroll
    for (int n = 0; n < 9; ++n){ e[n] = __expf(lg[n] - m); s += e[n]; }
    float inv = 1.f / s;

    float c0 = 0.f, c1 = 0.f, c2 = 0.f, c3 = 0.f;
#pragma unroll
    for (int n = 0; n < 9; ++n){
        float a = e[n] * inv;
        ushort4 v4 = *(const ushort4*)(qkv + rows[n] * QKVS + 512 + lane * 4);
        c0 += a * b2f(v4.x); c1 += a * b2f(v4.y);
        c2 += a * b2f(v4.z); c3 += a * b2f(v4.w);
    }
    ushort4 o; o.x = f2b(c0); o.y = f2b(c1); o.z = f2b(c2); o.w = f2b(c3);
    *(ushort4*)(ctx + (size_t)pix * 256 + lane * 4) = o;
}

// ---------------------------------------------------------------------------
extern "C" void kernel_launch(void* const* d_in, const int* in_sizes, int n_in,
                              void* d_out, int out_size, void* d_ws, size_t ws_size,
                              hipStream_t stream){
    const float* x  = (const float*)d_in[0];
    const float* Wq = (const float*)d_in[1];
    const float* bq = (const float*)d_in[2];
    const float* Wk = (const float*)d_in[3];
    const float* bk = (const float*)d_in[4];
    const float* Wv = (const float*)d_in[5];
    const float* bv = (const float*)d_in[6];
    const float* Wo = (const float*)d_in[7];
    const float* bo = (const float*)d_in[8];
    float* out = (float*)d_out;

    char* ws = (char*)d_ws;
    ushort* wtq    = (ushort*)(ws);                // [4][768][256] bf16
    ushort* wot    = (ushort*)(ws + 1572864);      // [256][256] bf16
    float*  biasp  = (float*) (ws + 1703936);      // [4][768]
    float*  psum   = (float*) (ws + 1716224);      // [256][256]
    float*  psum2  = (float*) (ws + 1978368);      // [256][256]
    ushort* xt     = (ushort*)(ws + 2240512);      // [MTOT][256] bf16
    ushort* qkv    = (ushort*)(ws + 11677696);     // [MTOT][768] bf16
    ushort* ctx    = (ushort*)(ws + 39989248);     // [NPIX][256] bf16

    ln_fuse<<<512, 256, 0, stream>>>(x, xt, psum, psum2);
    prep2<<<332, 256, 0, stream>>>(Wq, bq, Wk, bk, Wv, bv, Wo,
                                   psum, psum2, wtq, wot, biasp, xt);

    gemm_qkv<<<216, 512, 0, stream>>>(xt, wtq, biasp, qkv);   // 72 M x 3 N tiles

    attn_win<<<4096, 256, 0, stream>>>(qkv, ctx);

    dim3 g2(2, 128);
    gemm_out<<<g2, 256, 0, stream>>>(wot, ctx, bo, out);
}